// Round 1
// baseline (214.162 us; speedup 1.0000x reference)
//
#include <hip/hip_runtime.h>

// ContourIntegrationLayer: depthwise 3x3 conv, center tap masked to 0,
// SAME padding, + residual. x: [B,H,W,C] fp32 NHWC, kernel: [3,3,C] fp32.
// B=32 H=56 W=56 C=256.

#define BB 32
#define HH 56
#define WW 56
#define CC 256
#define C4 (CC / 4)  // 64 float4 groups per pixel

__global__ __launch_bounds__(256) void contour_kernel(
    const float4* __restrict__ x,     // [B*H*W*C4]
    const float4* __restrict__ kern,  // [9*C4]
    float4* __restrict__ out)         // [B*H*W*C4]
{
    int idx = blockIdx.x * blockDim.x + threadIdx.x;
    // layout: idx = ((b*H + h)*W + w)*C4 + c4
    int c4 = idx & (C4 - 1);
    int t  = idx >> 6;            // pixel index
    int w  = t % WW;
    t /= WW;
    int h  = t % HH;
    int b  = t / HH;
    if (b >= BB) return;

    int base = idx;               // ((b*H+h)*W + w)*C4 + c4
    float4 ctr = x[base];
    float4 acc = ctr;             // residual add

    #pragma unroll
    for (int ky = 0; ky < 3; ++ky) {
        int hh = h + ky - 1;
        if (hh < 0 || hh >= HH) continue;
        #pragma unroll
        for (int kx = 0; kx < 3; ++kx) {
            if (ky == 1 && kx == 1) continue;   // masked center tap
            int ww = w + kx - 1;
            if (ww < 0 || ww >= WW) continue;
            float4 xv = x[((b * HH + hh) * WW + ww) * C4 + c4];
            float4 kv = kern[(ky * 3 + kx) * C4 + c4];
            acc.x += xv.x * kv.x;
            acc.y += xv.y * kv.y;
            acc.z += xv.z * kv.z;
            acc.w += xv.w * kv.w;
        }
    }
    out[base] = acc;
}

extern "C" void kernel_launch(void* const* d_in, const int* in_sizes, int n_in,
                              void* d_out, int out_size, void* d_ws, size_t ws_size,
                              hipStream_t stream) {
    const float4* x    = (const float4*)d_in[0];
    const float4* kern = (const float4*)d_in[1];
    float4* out        = (float4*)d_out;

    const int total = BB * HH * WW * C4;          // 6,422,528 threads
    const int block = 256;
    const int grid  = (total + block - 1) / block; // 25,088 blocks
    contour_kernel<<<grid, block, 0, stream>>>(x, kern, out);
}

// Round 2
// 211.665 us; speedup vs baseline: 1.0118x; 1.0118x over previous
//
#include <hip/hip_runtime.h>

// ContourIntegrationLayer: depthwise 3x3 conv, center tap masked to 0,
// SAME padding, + residual. x: [B,H,W,C] fp32 NHWC, kernel: [3,3,C] fp32.
// B=32 H=56 W=56 C=256.
//
// R1: XCD-aware block swizzle. Blocks are dispatched round-robin across the
// 8 XCDs; remapping block IDs so each XCD owns a contiguous chunk (exactly 4
// whole images) keeps the 3-row reuse window (~170 KB) resident in that
// XCD's 4 MiB L2. R0 showed 2.1x x-overfetch without this.

#define BB 32
#define HH 56
#define WW 56
#define CC 256
#define C4 (CC / 4)   // 64 float4 groups per pixel
#define NXCD 8

__global__ __launch_bounds__(256) void contour_kernel(
    const float4* __restrict__ x,     // [B*H*W*C4]
    const float4* __restrict__ kern,  // [9*C4]
    float4* __restrict__ out)         // [B*H*W*C4]
{
    // XCD swizzle: hardware assigns blockIdx.x -> XCD (blockIdx.x % 8).
    // Remap so XCD k processes contiguous chunk k of the problem.
    const int nblocks   = gridDim.x;            // 25088, divisible by 8
    const int per_xcd   = nblocks / NXCD;       // 3136 = 4 images
    const int xcd       = blockIdx.x % NXCD;
    const int local     = blockIdx.x / NXCD;
    const int blk       = xcd * per_xcd + local;

    int idx = blk * blockDim.x + threadIdx.x;
    // layout: idx = ((b*H + h)*W + w)*C4 + c4
    int c4 = idx & (C4 - 1);
    int t  = idx >> 6;            // pixel index
    int w  = t % WW;
    t /= WW;
    int h  = t % HH;
    int b  = t / HH;
    if (b >= BB) return;

    int base = idx;               // ((b*H+h)*W + w)*C4 + c4
    float4 ctr = x[base];
    float4 acc = ctr;             // residual add

    #pragma unroll
    for (int ky = 0; ky < 3; ++ky) {
        int hh = h + ky - 1;
        if (hh < 0 || hh >= HH) continue;
        #pragma unroll
        for (int kx = 0; kx < 3; ++kx) {
            if (ky == 1 && kx == 1) continue;   // masked center tap
            int ww = w + kx - 1;
            if (ww < 0 || ww >= WW) continue;
            float4 xv = x[((b * HH + hh) * WW + ww) * C4 + c4];
            float4 kv = kern[(ky * 3 + kx) * C4 + c4];
            acc.x += xv.x * kv.x;
            acc.y += xv.y * kv.y;
            acc.z += xv.z * kv.z;
            acc.w += xv.w * kv.w;
        }
    }
    out[base] = acc;
}

extern "C" void kernel_launch(void* const* d_in, const int* in_sizes, int n_in,
                              void* d_out, int out_size, void* d_ws, size_t ws_size,
                              hipStream_t stream) {
    const float4* x    = (const float4*)d_in[0];
    const float4* kern = (const float4*)d_in[1];
    float4* out        = (float4*)d_out;

    const int total = BB * HH * WW * C4;          // 6,422,528 threads
    const int block = 256;
    const int grid  = (total + block - 1) / block; // 25,088 blocks (8*3136)
    contour_kernel<<<grid, block, 0, stream>>>(x, kern, out);
}